// Round 1
// baseline (286.922 us; speedup 1.0000x reference)
//
#include <hip/hip_runtime.h>

// B=8, T=64, N=512, D=64, K=8 heads, d=8.
// One workgroup (256 thr = 4 waves) per (b,n). Full fusion.
// Restructure vs. 281us baseline:
//  - prep kernel pre-transposes weights to bf16 Wt[col][k] in d_ws (once per
//    launch); main-kernel B-fragments load straight from global (L2-hot).
//  - A (concat(x,ste)) fragments load straight from global into registers,
//    reused across all 3 QKV GEMMs. No h/wT LDS, no stageW.
//  - LDS: qb(+attnout overlay) | kb | vT | P(+FFN abuf overlay) = 36,864 B
//    -> 4 blocks/CU (was 2 @ 62,464 B).
//  - Exactly ONE __syncthreads per block (kb/vT are the only cross-wave
//    data). All other phase deps are intra-wave (wave w owns t-rows
//    16w..16w+15 end-to-end); compiler lgkmcnt ordering covers them.

#define Bb 8
#define Tt 64
#define Nn 512
#define Dd 64

typedef unsigned short u16;
typedef unsigned int u32;
typedef __bf16 bf16x8 __attribute__((ext_vector_type(8)));
typedef float f32x4 __attribute__((ext_vector_type(4)));
typedef short s16x8 __attribute__((ext_vector_type(8)));

// LDS strides in shorts: 72 = 36 dwords == 4 (mod 32) -> wave64 ds_read_b128
// bank-balanced; rows 16B-aligned.
#define QS 72
#define PS 72

// ws layout (u16): WtQ[64][128] @0, WtK @8192, WtV @16384,
//                  Wt1[64][64] @24576, Wt2 @28672. Total 32768 u16 = 64 KiB.
#define WSQ 0
#define WSK 8192
#define WSV 16384
#define WS1 24576
#define WS2 28672

__device__ inline u16 f2bf(float f) {             // fp32 -> bf16 RNE
    u32 x = __float_as_uint(f);
    x += 0x7fffu + ((x >> 16) & 1u);
    return (u16)(x >> 16);
}
__device__ inline bf16x8 ldf(const u16* p) { return *(const bf16x8*)p; }
__device__ inline bf16x8 zf8() {
    s16x8 z = {0, 0, 0, 0, 0, 0, 0, 0};
    return __builtin_bit_cast(bf16x8, z);
}
__device__ inline bf16x8 pack8(float4 a, float4 b) {
    s16x8 r;
    r[0] = (short)f2bf(a.x); r[1] = (short)f2bf(a.y);
    r[2] = (short)f2bf(a.z); r[3] = (short)f2bf(a.w);
    r[4] = (short)f2bf(b.x); r[5] = (short)f2bf(b.y);
    r[6] = (short)f2bf(b.z); r[7] = (short)f2bf(b.w);
    return __builtin_bit_cast(bf16x8, r);
}

// 64x64 GEMM. A: registers (AREG, QKV) or LDS rows (FFN). B: global bf16
// Wt[col][KD] (L2-hot weights). Wave w computes rows 16w..16w+15, 4 col-tiles.
// MODE 0: relu -> bf16 LDS row-major; MODE 1: relu -> bf16 LDS transposed
// (O[col][row], for vT); MODE 2: no relu -> fp32 global (row stride N*D).
template<int KD, int MODE, bool AREG>
__device__ inline void gemm(const bf16x8* afr,
                            const u16* aLds, int As,
                            const u16* __restrict__ WtG,
                            const float* __restrict__ bias,
                            u16* O, int Os, float* G,
                            int w, int lane, float scale) {
    const int l15 = lane & 15, qd = lane >> 4;
    f32x4 acc[4] = {{0,0,0,0},{0,0,0,0},{0,0,0,0},{0,0,0,0}};
#pragma unroll
    for (int c = 0; c < KD / 32; ++c) {
        bf16x8 af = AREG ? afr[c]
                         : ldf(&aLds[(16 * w + l15) * As + c * 32 + qd * 8]);
#pragma unroll
        for (int ct = 0; ct < 4; ++ct) {
            bf16x8 bfr = *(const bf16x8*)&WtG[(16 * ct + l15) * KD + c * 32 + qd * 8];
            acc[ct] = __builtin_amdgcn_mfma_f32_16x16x32_bf16(af, bfr, acc[ct], 0, 0, 0);
        }
    }
#pragma unroll
    for (int ct = 0; ct < 4; ++ct) {
        const int col = 16 * ct + l15;
        const float bv = bias[col];
#pragma unroll
        for (int r = 0; r < 4; ++r) {
            const int row = 16 * w + 4 * qd + r;
            float v = acc[ct][r] + bv;
            if (MODE != 2) v = fmaxf(v, 0.f);
            v *= scale;
            if (MODE == 0)      O[row * Os + col] = f2bf(v);
            else if (MODE == 1) O[col * Os + row] = f2bf(v);
            else                G[(size_t)row * (Nn * Dd) + col] = v;
        }
    }
}

// One-time weight transpose+convert: Wt[c][k] = bf16(W[k][c]).
__global__ __launch_bounds__(256)
void prep_w(const float* __restrict__ Wq, const float* __restrict__ Wk,
            const float* __restrict__ Wv, const float* __restrict__ W1,
            const float* __restrict__ W2, u16* __restrict__ ws) {
    int i = blockIdx.x * 256 + threadIdx.x;
    if (i < 24576) {                       // Wq/Wk/Wv: [128][64] each
        int m = i >> 13;                   // matrix id
        int r = i & 8191;                  // r = k*64 + c (coalesced read)
        int k = r >> 6, c = r & 63;
        const float* W = (m == 0) ? Wq : (m == 1) ? Wk : Wv;
        ws[m * 8192 + c * 128 + k] = f2bf(W[r]);
    } else if (i < 32768) {                // W1/W2: [64][64] each
        int j = i - 24576;
        int m = j >> 12;
        int r = j & 4095;
        int k = r >> 6, c = r & 63;
        const float* W = (m == 0) ? W1 : W2;
        ws[24576 + m * 4096 + c * 64 + k] = f2bf(W[r]);
    }
}

__global__ __launch_bounds__(256, 4)
void ta_fused_kernel(const float* __restrict__ x,  const float* __restrict__ ste,
                     const float* __restrict__ bq, const float* __restrict__ bk,
                     const float* __restrict__ bv, const float* __restrict__ b1,
                     const float* __restrict__ b2, const u16* __restrict__ ws,
                     float* __restrict__ out) {
    // LDS map (shorts), 18432 total = 36,864 B:
    //   qb [64][72] @ 0      (attnout overlays: head h8 writes cols h8..h8+7
    //                         of its own wave's rows AFTER reading them)
    //   kb [64][72] @ 4608
    //   vT [64][72] @ 9216   (vT[dim][s])
    //   P  4x[16][72] @13824 (wave-private; FFN abuf overlays: absolute row
    //                         indexing (16w+r)*72 lands exactly in slice w)
    __shared__ __align__(16) u16 sm[18432];
    u16* qb = sm;
    u16* kb = sm + 4608;
    u16* vT = sm + 9216;
    u16* pB = sm + 13824;

    const int tid  = threadIdx.x;
    const int w    = tid >> 6;
    const int lane = tid & 63;
    const int l15  = lane & 15, qd = lane >> 4;
    const int bid  = blockIdx.x;
    const int b = bid >> 9, n = bid & 511;

    // ---- Phase 0: A-fragments (concat(x,ste) row 16w+l15) -> registers ----
    const int t = 16 * w + l15;
    const float* xr = x   + (((size_t)b * Tt + t) * Nn + n) * Dd;
    const float* sr = ste + (((size_t)b * Tt + t) * Nn + n) * Dd;
    bf16x8 af[4];
#pragma unroll
    for (int c = 0; c < 2; ++c) {
        float4 p0 = *(const float4*)(xr + c * 32 + qd * 8);
        float4 p1 = *(const float4*)(xr + c * 32 + qd * 8 + 4);
        af[c] = pack8(p0, p1);
    }
#pragma unroll
    for (int c = 0; c < 2; ++c) {
        float4 p0 = *(const float4*)(sr + c * 32 + qd * 8);
        float4 p1 = *(const float4*)(sr + c * 32 + qd * 8 + 4);
        af[c + 2] = pack8(p0, p1);
    }

    // ---- Phase 1: QKV (B-fragments from global bf16 Wt, L2-hot) ----
    // 1/sqrt(8) folded into q.
    gemm<128, 0, true>(af, nullptr, 0, ws + WSQ, bq, qb, QS, nullptr, w, lane,
                       0.35355339059327373f);
    gemm<128, 0, true>(af, nullptr, 0, ws + WSK, bk, kb, QS, nullptr, w, lane, 1.f);
    gemm<128, 1, true>(af, nullptr, 0, ws + WSV, bv, vT, QS, nullptr, w, lane, 1.f);
    __syncthreads();   // the ONLY barrier: kb/vT are read cross-wave below

    // ---- Phase 2: attention. Wave w owns t-rows 16w..16w+15, all 8 heads.
    u16* pb = pB + 1152 * w;                // wave-private P slice [16][72]
    u16* attnout = qb;                      // overlay (see LDS map)
    const bf16x8 z8 = zf8();
#pragma unroll 1
    for (int h8 = 0; h8 < 64; h8 += 8) {
        // scores: S[t][s] = q . k, K padded 8->32 (quads 1-3 zeroed both sides)
        bf16x8 qa = (qd == 0) ? ldf(&qb[(16 * w + l15) * QS + h8]) : z8;
        f32x4 sv[4] = {{0,0,0,0},{0,0,0,0},{0,0,0,0},{0,0,0,0}};
#pragma unroll
        for (int ct = 0; ct < 4; ++ct) {
            bf16x8 bfr = (qd == 0) ? ldf(&kb[(16 * ct + l15) * QS + h8]) : z8;
            sv[ct] = __builtin_amdgcn_mfma_f32_16x16x32_bf16(qa, bfr, sv[ct], 0, 0, 0);
        }
        // mask + exp (scores small: no max-subtraction; masked entries are
        // exactly 0, matching exp(-32767-m) underflow)
        const int tr = 16 * w + 4 * qd;
#pragma unroll
        for (int ct = 0; ct < 4; ++ct) {
            const int sc = 16 * ct + l15;
#pragma unroll
            for (int r = 0; r < 4; ++r)
                sv[ct][r] = (sc <= tr + r) ? __expf(sv[ct][r]) : 0.f;
        }
        // row denominators: in-lane over ct, then butterfly over 16-lane group
        f32x4 dsum = sv[0] + sv[1] + sv[2] + sv[3];
#pragma unroll
        for (int m = 1; m <= 8; m <<= 1) {
#pragma unroll
            for (int r = 0; r < 4; ++r)
                dsum[r] += __shfl_xor(dsum[r], m, 64);
        }
        // P (unnormalized) -> wave-private LDS slice, A-layout-readable
#pragma unroll
        for (int ct = 0; ct < 4; ++ct)
#pragma unroll
            for (int r = 0; r < 4; ++r)
                pb[(4 * qd + r) * PS + 16 * ct + l15] = f2bf(sv[ct][r]);
        // PV: out(16x8) = P(16x64) @ V_h(64x8), N padded 8->16
        f32x4 o = {0, 0, 0, 0};
#pragma unroll
        for (int k0 = 0; k0 < 64; k0 += 32) {
            bf16x8 pa = ldf(&pb[l15 * PS + k0 + qd * 8]);
            int vrow = h8 + (l15 & 7);      // clamped in-bounds for pad lanes
            bf16x8 vfr = (l15 < 8) ? ldf(&vT[vrow * QS + k0 + qd * 8]) : z8;
            o = __builtin_amdgcn_mfma_f32_16x16x32_bf16(pa, vfr, o, 0, 0, 0);
        }
        if (l15 < 8) {
#pragma unroll
            for (int r = 0; r < 4; ++r) {
                float inv = __builtin_amdgcn_rcpf(dsum[r]);
                attnout[(16 * w + 4 * qd + r) * QS + h8 + l15] = f2bf(o[r] * inv);
            }
        }
    }
    // No barrier: FFN A-operands are the wave's own rows (attnout=qb overlay),
    // abuf is the wave's own P slice. Intra-wave LDS ordering suffices.

    // ---- Phase 3: FFN ----
    gemm<64, 0, false>(nullptr, attnout, QS, ws + WS1, b1, pB, QS, nullptr,
                       w, lane, 1.f);
    float* ob = out + (((size_t)b * Tt) * Nn + n) * Dd;
    gemm<64, 2, false>(nullptr, pB, QS, ws + WS2, b2, nullptr, 0, ob,
                       w, lane, 1.f);
}

extern "C" void kernel_launch(void* const* d_in, const int* in_sizes, int n_in,
                              void* d_out, int out_size, void* d_ws, size_t ws_size,
                              hipStream_t stream) {
    const float* x   = (const float*)d_in[0];
    const float* ste = (const float*)d_in[1];
    const float* Wq  = (const float*)d_in[2];
    const float* bq  = (const float*)d_in[3];
    const float* Wk  = (const float*)d_in[4];
    const float* bk  = (const float*)d_in[5];
    const float* Wv  = (const float*)d_in[6];
    const float* bv  = (const float*)d_in[7];
    const float* W1  = (const float*)d_in[8];
    const float* b1  = (const float*)d_in[9];
    const float* W2  = (const float*)d_in[10];
    const float* b2  = (const float*)d_in[11];
    float* out = (float*)d_out;
    u16* ws = (u16*)d_ws;

    hipLaunchKernelGGL(prep_w, dim3(128), dim3(256), 0, stream,
                       Wq, Wk, Wv, W1, W2, ws);
    hipLaunchKernelGGL(ta_fused_kernel, dim3(Bb * Nn), dim3(256), 0, stream,
                       x, ste, bq, bk, bv, b1, b2, ws, out);
}